// Round 1
// baseline (181.911 us; speedup 1.0000x reference)
//
#include <hip/hip_runtime.h>
#include <stdint.h>

// Problem: cosine-similarity relations.
//   support: (2,5,1024,128) fp32 -> 10240 rows; query: (2,4,1024,128) -> 8192 rows
//   out: (2,4,5,1024,1024) fp32 = 167.8 MB  -> write-BW-bound (~27 us floor)
// Plan: normalize+cast to bf16 (kernel 1, d_ws), 40 batched bf16-MFMA GEMMs
// C = Qn * Sn^T (kernel 2, m97-style: global_load_lds w=16, whole K=128 in LDS).

#define S_ROWS 10240
#define Q_ROWS 8192

typedef __attribute__((ext_vector_type(8))) short short8;   // 8 bf16 (4 VGPRs)
typedef __attribute__((ext_vector_type(4))) float floatx4;  // 16x16 MFMA acc

__device__ static inline unsigned short f32_to_bf16_rne(float f) {
    union { float f; uint32_t u; } c; c.f = f;
    uint32_t u = c.u;
    uint32_t r = u + 0x7FFFu + ((u >> 16) & 1u);   // round-to-nearest-even
    return (unsigned short)(r >> 16);
}

// ---------------- Kernel 1: L2-normalize rows of 128, cast to bf16 ----------
__global__ __launch_bounds__(256) void norm_cast_kernel(
    const float* __restrict__ support, const float* __restrict__ query,
    unsigned short* __restrict__ sn, unsigned short* __restrict__ qn)
{
    int wave = blockIdx.x * 4 + (threadIdx.x >> 6);
    int lane = threadIdx.x & 63;

    const float* src;
    unsigned short* dst;
    if (wave < S_ROWS) {
        src = support + (size_t)wave * 128;
        dst = sn + (size_t)wave * 128;
    } else {
        int r = wave - S_ROWS;
        src = query + (size_t)r * 128;
        dst = qn + (size_t)r * 128;
    }

    float2 v = ((const float2*)src)[lane];
    float s = v.x * v.x + v.y * v.y;
    #pragma unroll
    for (int off = 32; off > 0; off >>= 1) s += __shfl_xor(s, off, 64);
    float inv = 1.0f / fmaxf(sqrtf(s), 1e-12f);

    unsigned short lo = f32_to_bf16_rne(v.x * inv);
    unsigned short hi = f32_to_bf16_rne(v.y * inv);
    ((uint32_t*)dst)[lane] = ((uint32_t)hi << 16) | (uint32_t)lo;
}

// ---------------- Kernel 2: batched C = Qn * Sn^T via bf16 MFMA -------------
__device__ static inline void gl2lds16(const unsigned short* g, unsigned short* l) {
    __builtin_amdgcn_global_load_lds(
        (const __attribute__((address_space(1))) void*)g,
        (__attribute__((address_space(3))) void*)l,
        16, 0, 0);
}

__global__ __launch_bounds__(256) void gemm_bt_kernel(
    const unsigned short* __restrict__ qn, const unsigned short* __restrict__ sn,
    float* __restrict__ out)
{
    __shared__ unsigned short As[128 * 128];  // 32 KB, rows m, k contiguous
    __shared__ unsigned short Bs[128 * 128];  // 32 KB, rows n, k contiguous

    const int tid  = threadIdx.x;
    const int wave = tid >> 6;
    const int lane = tid & 63;

    const int tn = blockIdx.x & 7;
    const int tm = blockIdx.x >> 3;
    const int y   = blockIdx.y;          // 0..39 -> (b,i,j)
    const int b   = y / 20;
    const int rem = y % 20;
    const int i   = rem / 5;
    const int j   = rem % 5;

    const unsigned short* gA = qn + (((size_t)(b * 4 + i) * 1024 + tm * 128) * 128);
    const unsigned short* gB = sn + (((size_t)(b * 5 + j) * 1024 + tn * 128) * 128);

    // Stage 32 KB contiguous per tile. Per call: wave-uniform LDS base,
    // HW scatters lane i at base + i*16 B; global src = gX + base + lane*16 B.
    #pragma unroll
    for (int it = 0; it < 8; ++it) {
        const int base = it * 2048 + wave * 512;   // in ushorts (2048 = 256 lanes * 8)
        gl2lds16(gA + base + lane * 8, &As[base]);
        gl2lds16(gB + base + lane * 8, &Bs[base]);
    }

    const int wm   = (wave >> 1) * 64;
    const int wn   = (wave & 1) * 64;
    const int ml   = lane & 15;
    const int quad = lane >> 4;

    floatx4 acc[4][4] = {};

    __syncthreads();   // drains vmcnt (global_load_lds) + barrier

    #pragma unroll
    for (int kb = 0; kb < 4; ++kb) {
        const int koff = kb * 32 + quad * 8;
        short8 a[4], bf[4];
        #pragma unroll
        for (int mi = 0; mi < 4; ++mi)
            a[mi] = *(const short8*)&As[(wm + mi * 16 + ml) * 128 + koff];
        #pragma unroll
        for (int ni = 0; ni < 4; ++ni)
            bf[ni] = *(const short8*)&Bs[(wn + ni * 16 + ml) * 128 + koff];
        #pragma unroll
        for (int mi = 0; mi < 4; ++mi)
            #pragma unroll
            for (int ni = 0; ni < 4; ++ni)
                acc[mi][ni] = __builtin_amdgcn_mfma_f32_16x16x32_bf16(
                    a[mi], bf[ni], acc[mi][ni], 0, 0, 0);
    }

    // Epilogue: C/D layout col=lane&15, row=quad*4+reg (m89/m91-verified).
    float* gC = out + ((size_t)((b * 4 + i) * 5 + j) << 20)
                    + (size_t)(tm * 128) * 1024 + tn * 128;
    #pragma unroll
    for (int mi = 0; mi < 4; ++mi) {
        #pragma unroll
        for (int r = 0; r < 4; ++r) {
            const int row = wm + mi * 16 + quad * 4 + r;
            float* rowp = gC + (size_t)row * 1024 + wn + ml;
            #pragma unroll
            for (int ni = 0; ni < 4; ++ni)
                rowp[ni * 16] = acc[mi][ni][r];
        }
    }
}

extern "C" void kernel_launch(void* const* d_in, const int* in_sizes, int n_in,
                              void* d_out, int out_size, void* d_ws, size_t ws_size,
                              hipStream_t stream) {
    const float* support = (const float*)d_in[0];   // (2,5,1024,128)
    const float* query   = (const float*)d_in[1];   // (2,4,1024,128)
    unsigned short* sn = (unsigned short*)d_ws;             // 10240*128 bf16
    unsigned short* qn = sn + (size_t)S_ROWS * 128;         //  8192*128 bf16
    float* out = (float*)d_out;

    norm_cast_kernel<<<dim3((S_ROWS + Q_ROWS) / 4), dim3(256), 0, stream>>>(
        support, query, sn, qn);
    gemm_bt_kernel<<<dim3(64, 40), dim3(256), 0, stream>>>(qn, sn, out);
}